// Round 1
// baseline (434.129 us; speedup 1.0000x reference)
//
#include <hip/hip_runtime.h>
#include <stdint.h>

// Problem constants (from reference)
#define IN_F   4096
#define OUT_F  4096
#define M_ROWS 8192      // 4 * 2048
#define GROUPSIZE 128

// ---- types ----
typedef __attribute__((ext_vector_type(8))) short  bf16x8;  // 8 bf16 (4 VGPRs)
typedef __attribute__((ext_vector_type(4))) float  f32x4;   // MFMA accumulator

// fp32 -> bf16 (round-to-nearest-even), bit-level (no type headaches)
__device__ __forceinline__ short f2bf(float f) {
    union { float f; uint32_t u; } v; v.f = f;
    uint32_t r = v.u + 0x7FFFu + ((v.u >> 16) & 1u);
    return (short)(r >> 16);
}

// async global->LDS, 16B per lane (wave-uniform LDS base + lane*16)
__device__ __forceinline__ void load_lds16(const void* gsrc, void* lds) {
    __builtin_amdgcn_global_load_lds(
        (const __attribute__((address_space(1))) uint32_t*)gsrc,
        (__attribute__((address_space(3))) uint32_t*)lds,
        16, 0, 0);
}

// ============================================================================
// Kernel 1: GPTQ dequant -> W^T bf16 [OUT_F][IN_F]
// thread t: n = t>>9, kw = t&511 (one int32 word = 8 consecutive k for fixed n)
// write: WT[n][kw*8 .. kw*8+7]  (consecutive threads -> consecutive 16B: coalesced)
// ============================================================================
__global__ void dequant_wt_kernel(const int* __restrict__ qweight,   // [IN_F/8][OUT_F]
                                  const int* __restrict__ qzeros,    // [32][OUT_F/8]
                                  const float* __restrict__ scales,  // [32][OUT_F]
                                  short* __restrict__ wt)             // [OUT_F][IN_F] bf16
{
    int t  = blockIdx.x * blockDim.x + threadIdx.x;   // 0 .. 4096*512-1
    int n  = t >> 9;         // output column
    int kw = t & 511;        // k-word index (k = kw*8 + i)
    int g  = kw >> 4;        // group = (kw*8)/128

    float s = scales[g * OUT_F + n];
    uint32_t zw = (uint32_t)qzeros[g * (OUT_F / 8) + (n >> 3)];
    float z1 = (float)((zw >> (4 * (n & 7))) & 0xFu) + 1.0f;

    uint32_t q = (uint32_t)qweight[kw * OUT_F + n];

    bf16x8 out;
#pragma unroll
    for (int i = 0; i < 8; ++i) {
        float w = s * ((float)((q >> (4 * i)) & 0xFu) - z1);
        out[i] = f2bf(w);
    }
    *reinterpret_cast<bf16x8*>(&wt[(size_t)n * IN_F + kw * 8]) = out;
}

// ============================================================================
// Kernel 2: C[M][N] = X[M][K](fp32, converted to bf16) * WT[N][K](bf16)
// 128x128 tile, BK=64, 256 threads = 4 waves (2x2), each wave 64x64 out
// mfma_f32_16x16x32_bf16; A reg-staged (fp32->bf16 cvt), B via global_load_lds
// ============================================================================
#define BM 128
#define BN 128
#define BK 64
#define KTILES (IN_F / BK)   // 64

__global__ __launch_bounds__(256, 2) void gemm_x_wt_kernel(
    const float* __restrict__ X,    // [M_ROWS][IN_F]
    const short* __restrict__ WT,   // [OUT_F][IN_F] bf16 bits
    float* __restrict__ C)          // [M_ROWS][OUT_F]
{
    __shared__ short As[BM * BK];   // 16 KB, linear [r][c] r=M-row, c=k
    __shared__ short Bs[BN * BK];   // 16 KB, linear [r][c] r=N-col, c=k

    const int bn = blockIdx.x;      // 0..31  (fastest: one bm-row co-runs)
    const int bm = blockIdx.y;      // 0..63
    const int tid  = threadIdx.x;
    const int lane = tid & 63;
    const int wid  = tid >> 6;      // 0..3
    const int wr   = wid >> 1;      // wave M position (0..1)
    const int wc   = wid & 1;       // wave N position (0..1)

    const int row0 = bm * BM;
    const int col0 = bn * BN;

    const int frow = lane & 15;        // fragment row/col within 16
    const int fk   = (lane >> 4) * 8;  // fragment k-offset within 32

    f32x4 acc[4][4] = {};

    for (int kt = 0; kt < KTILES; ++kt) {
        // ---- A: global fp32 -> regs (issued before barrier: overlaps prev MFMA)
        float4 a0[4], a1[4];
#pragma unroll
        for (int j = 0; j < 4; ++j) {
            const int flat = (j * 256 + tid) * 8;
            const int r = flat >> 6;          // /BK
            const int c = flat & (BK - 1);
            const float* src = X + (size_t)(row0 + r) * IN_F + kt * BK + c;
            a0[j] = *reinterpret_cast<const float4*>(src);
            a1[j] = *reinterpret_cast<const float4*>(src + 4);
        }

        __syncthreads();   // all waves done reading LDS of previous tile

        // ---- B: async global->LDS (linear LDS layout, lane order == layout order)
#pragma unroll
        for (int j = 0; j < 4; ++j) {
            const int flat = (j * 256 + tid) * 8;
            const int r = flat >> 6;
            const int c = flat & (BK - 1);
            load_lds16(WT + (size_t)(col0 + r) * IN_F + kt * BK + c, &Bs[flat]);
        }

        // ---- A: convert + ds_write_b128
#pragma unroll
        for (int j = 0; j < 4; ++j) {
            const int flat = (j * 256 + tid) * 8;
            bf16x8 h;
            h[0] = f2bf(a0[j].x); h[1] = f2bf(a0[j].y);
            h[2] = f2bf(a0[j].z); h[3] = f2bf(a0[j].w);
            h[4] = f2bf(a1[j].x); h[5] = f2bf(a1[j].y);
            h[6] = f2bf(a1[j].z); h[7] = f2bf(a1[j].w);
            *reinterpret_cast<bf16x8*>(&As[flat]) = h;
        }

        __syncthreads();   // staging visible (compiler drains vmcnt/lgkmcnt)

        // ---- compute: 2 sub-K steps of 32
#pragma unroll
        for (int s = 0; s < 2; ++s) {
            bf16x8 af[4], bfr[4];
#pragma unroll
            for (int m = 0; m < 4; ++m) {
                const int row = wr * 64 + m * 16 + frow;
                af[m] = *reinterpret_cast<const bf16x8*>(&As[row * BK + s * 32 + fk]);
            }
#pragma unroll
            for (int n = 0; n < 4; ++n) {
                const int col = wc * 64 + n * 16 + frow;
                bfr[n] = *reinterpret_cast<const bf16x8*>(&Bs[col * BK + s * 32 + fk]);
            }
#pragma unroll
            for (int m = 0; m < 4; ++m)
#pragma unroll
                for (int n = 0; n < 4; ++n)
                    acc[m][n] = __builtin_amdgcn_mfma_f32_16x16x32_bf16(
                        af[m], bfr[n], acc[m][n], 0, 0, 0);
        }
    }

    // ---- C write: verified C/D layout (m89/m91): col=lane&15, row=(lane>>4)*4+reg
    const int crow = (lane >> 4) * 4;
    const int ccol = lane & 15;
#pragma unroll
    for (int m = 0; m < 4; ++m)
#pragma unroll
        for (int n = 0; n < 4; ++n)
#pragma unroll
            for (int r = 0; r < 4; ++r) {
                const int row = row0 + wr * 64 + m * 16 + crow + r;
                const int col = col0 + wc * 64 + n * 16 + ccol;
                C[(size_t)row * OUT_F + col] = acc[m][n][r];
            }
}

// ============================================================================
extern "C" void kernel_launch(void* const* d_in, const int* in_sizes, int n_in,
                              void* d_out, int out_size, void* d_ws, size_t ws_size,
                              hipStream_t stream) {
    const float* x       = (const float*)d_in[0];  // [4,2048,4096] fp32
    const int*   qweight = (const int*)  d_in[1];  // [512,4096]
    const int*   qzeros  = (const int*)  d_in[2];  // [32,512]
    const float* scales  = (const float*)d_in[3];  // [32,4096]
    float*       out     = (float*)d_out;          // [4,2048,4096] fp32

    short* wt = (short*)d_ws;                      // W^T bf16 [OUT_F][IN_F] = 33.5 MB

    // 1) dequant: 4096*512 threads
    dequant_wt_kernel<<<(OUT_F * (IN_F / 8)) / 256, 256, 0, stream>>>(
        qweight, qzeros, scales, wt);

    // 2) GEMM: grid (N-tiles fastest for A-panel L2/L3 reuse)
    dim3 grid(OUT_F / BN, M_ROWS / BM);   // (32, 64)
    gemm_x_wt_kernel<<<grid, 256, 0, stream>>>(x, wt, out);
}

// Round 2
// 318.116 us; speedup vs baseline: 1.3647x; 1.3647x over previous
//
#include <hip/hip_runtime.h>
#include <stdint.h>

// Problem constants
#define IN_F   4096
#define OUT_F  4096
#define M_ROWS 8192      // 4 * 2048
#define KT     (IN_F / 64)   // 64 K-tiles of BK=64

typedef __attribute__((ext_vector_type(8))) short  bf16x8;
typedef __attribute__((ext_vector_type(4))) float  f32x4;

__device__ __forceinline__ short f2bf(float f) {
    union { float f; uint32_t u; } v; v.f = f;
    uint32_t r = v.u + 0x7FFFu + ((v.u >> 16) & 1u);
    return (short)(r >> 16);
}

__device__ __forceinline__ void load_lds16(const void* gsrc, void* lds) {
    __builtin_amdgcn_global_load_lds(
        (const __attribute__((address_space(1))) uint32_t*)gsrc,
        (__attribute__((address_space(3))) uint32_t*)lds,
        16, 0, 0);
}

// ============================================================================
// Kernel 1: GPTQ dequant -> W^T bf16 [OUT_F][IN_F]
// ============================================================================
__global__ void dequant_wt_kernel(const int* __restrict__ qweight,
                                  const int* __restrict__ qzeros,
                                  const float* __restrict__ scales,
                                  short* __restrict__ wt)
{
    int t  = blockIdx.x * blockDim.x + threadIdx.x;
    int n  = t >> 9;
    int kw = t & 511;
    int g  = kw >> 4;

    float s = scales[g * OUT_F + n];
    uint32_t zw = (uint32_t)qzeros[g * (OUT_F / 8) + (n >> 3)];
    float z1 = (float)((zw >> (4 * (n & 7))) & 0xFu) + 1.0f;
    uint32_t q = (uint32_t)qweight[kw * OUT_F + n];

    bf16x8 out;
#pragma unroll
    for (int i = 0; i < 8; ++i) {
        float w = s * ((float)((q >> (4 * i)) & 0xFu) - z1);
        out[i] = f2bf(w);
    }
    *reinterpret_cast<bf16x8*>(&wt[(size_t)n * IN_F + kw * 8]) = out;
}

// ============================================================================
// Kernel 2: X fp32 -> bf16 prepass
// ============================================================================
__global__ void xconv_kernel(const float* __restrict__ x, short* __restrict__ xb)
{
    int t = blockIdx.x * blockDim.x + threadIdx.x;   // one 8-elem chunk each
    const float4* src = reinterpret_cast<const float4*>(x) + (size_t)t * 2;
    float4 a = src[0], b = src[1];
    bf16x8 h;
    h[0] = f2bf(a.x); h[1] = f2bf(a.y); h[2] = f2bf(a.z); h[3] = f2bf(a.w);
    h[4] = f2bf(b.x); h[5] = f2bf(b.y); h[6] = f2bf(b.z); h[7] = f2bf(b.w);
    reinterpret_cast<bf16x8*>(xb)[t] = h;
}

// ============================================================================
// Kernel 3: 256x256 phase-split GEMM, bf16 MFMA, T2 swizzle + counted-ish vmcnt
//   C[M][N] = Xb[M][K] * WT[N][K]^T
//   512 thr = 8 waves (2M x 4N), per-wave 128x64 out, acc[8][4] f32x4
//   LDS: 2 slots x ([256][64] A + [256][64] B) bf16 = 128 KB
//   Swizzle: LDS[r][cb] holds tile[r][cb ^ ((r&7)<<4 bytes)]
//     - staged via pre-swizzled GLOBAL source (linear LDS dest, rule 21)
//     - ds_read applies same XOR on the k-byte offset
// ============================================================================
__global__ __launch_bounds__(512, 2) void gemm8_kernel(
    const short* __restrict__ Xb,   // [M_ROWS][IN_F] bf16
    const short* __restrict__ WT,   // [OUT_F][IN_F] bf16
    float* __restrict__ C)          // [M_ROWS][OUT_F]
{
    __shared__ short As[2][256 * 64];   // 32 KB per slot
    __shared__ short Bs[2][256 * 64];

    const int tid  = threadIdx.x;
    const int lane = tid & 63;
    const int wid  = tid >> 6;     // 0..7
    const int wr   = wid >> 2;     // 0..1  (M half)
    const int wc   = wid & 3;      // 0..3  (N quarter)

    const int row0 = blockIdx.y * 256;
    const int col0 = blockIdx.x * 256;

    // ---- staging geometry: load L covers slot bytes [L*8192 + tid*16, +16)
    const int rL0 = tid >> 3;                               // row for L=0
    const int csw = ((tid & 7) << 3) ^ ((rL0 & 7) << 3);    // pre-swizzled src col (elems)
    const short* gA[4]; const short* gB[4]; int dOff[4];
#pragma unroll
    for (int L = 0; L < 4; ++L) {
        const int r = L * 64 + rL0;
        gA[L] = Xb + (size_t)(row0 + r) * IN_F + csw;
        gB[L] = WT + (size_t)(col0 + r) * IN_F + csw;
        dOff[L] = L * 8192 + tid * 16;                      // bytes
    }

    // ---- read geometry
    const int frow = lane & 15;
    const int k0   = ((lane >> 4) << 4) ^ ((frow & 7) << 4); // swizzled kbyte, ks=0
    // ks=1 address = base + (k0 ^ 64)

    f32x4 acc[8][4] = {};

    // ---- prologue: stage tile 0 -> slot 0
#pragma unroll
    for (int L = 0; L < 4; ++L) load_lds16(gA[L], (char*)As[0] + dOff[L]);
#pragma unroll
    for (int L = 0; L < 4; ++L) load_lds16(gB[L], (char*)Bs[0] + dOff[L]);
    asm volatile("s_waitcnt vmcnt(0)" ::: "memory");
    __builtin_amdgcn_s_barrier();

    for (int t = 0; t < KT; ++t) {
        const int s = t & 1;
        char* Ab = (char*)As[s];
        char* Bb = (char*)Bs[s];
        char* An = (char*)As[s ^ 1];
        char* Bn = (char*)Bs[s ^ 1];
        const bool pf = (t < KT - 1);

#pragma unroll
        for (int q = 0; q < 4; ++q) {      // 4 phases: C-quadrants
            const int mq = q >> 1, nq = q & 1;

            // -- ds reads for this quadrant (12 x ds_read_b128)
            bf16x8 af[4][2]; bf16x8 bfr[2][2];
#pragma unroll
            for (int m = 0; m < 4; ++m) {
                const int r = wr * 128 + (mq * 4 + m) * 16 + frow;
                char* base = Ab + r * 128;
                af[m][0] = *reinterpret_cast<const bf16x8*>(base + k0);
                af[m][1] = *reinterpret_cast<const bf16x8*>(base + (k0 ^ 64));
            }
#pragma unroll
            for (int n = 0; n < 2; ++n) {
                const int r = wc * 64 + (nq * 2 + n) * 16 + frow;
                char* base = Bb + r * 128;
                bfr[n][0] = *reinterpret_cast<const bf16x8*>(base + k0);
                bfr[n][1] = *reinterpret_cast<const bf16x8*>(base + (k0 ^ 64));
            }

            // -- staging issue: tile t+1 into idle slot (A at q0, B at q1)
            if (q == 0 && pf) {
#pragma unroll
                for (int L = 0; L < 4; ++L)
                    load_lds16(gA[L] + (size_t)(t + 1) * 64, An + dOff[L]);
            }
            if (q == 1 && pf) {
#pragma unroll
                for (int L = 0; L < 4; ++L)
                    load_lds16(gB[L] + (size_t)(t + 1) * 64, Bn + dOff[L]);
            }

            __builtin_amdgcn_s_barrier();
            asm volatile("s_waitcnt lgkmcnt(0)" ::: "memory");
            __builtin_amdgcn_sched_barrier(0);   // rule 18: pin MFMA after the wait

            __builtin_amdgcn_s_setprio(1);
#pragma unroll
            for (int m = 0; m < 4; ++m)
#pragma unroll
                for (int n = 0; n < 2; ++n) {
                    acc[mq * 4 + m][nq * 2 + n] =
                        __builtin_amdgcn_mfma_f32_16x16x32_bf16(
                            af[m][0], bfr[n][0], acc[mq * 4 + m][nq * 2 + n], 0, 0, 0);
                    acc[mq * 4 + m][nq * 2 + n] =
                        __builtin_amdgcn_mfma_f32_16x16x32_bf16(
                            af[m][1], bfr[n][1], acc[mq * 4 + m][nq * 2 + n], 0, 0, 0);
                }
            __builtin_amdgcn_s_setprio(0);

            if (q == 3 && pf)   // tile t+1 fully landed before next iteration reads it
                asm volatile("s_waitcnt vmcnt(0)" ::: "memory");
            __builtin_amdgcn_s_barrier();
        }
    }

    // ---- epilogue: C/D layout col=lane&15, row=(lane>>4)*4+reg (verified r1)
    const int crow = (lane >> 4) * 4;
    const int ccol = lane & 15;
#pragma unroll
    for (int fm = 0; fm < 8; ++fm)
#pragma unroll
        for (int fn = 0; fn < 4; ++fn)
#pragma unroll
            for (int r = 0; r < 4; ++r) {
                const int row = row0 + wr * 128 + fm * 16 + crow + r;
                const int col = col0 + wc * 64 + fn * 16 + ccol;
                C[(size_t)row * OUT_F + col] = acc[fm][fn][r];
            }
}

// ============================================================================
// Fallback GEMM (round-1, verified): used only if ws too small for Xb
// ============================================================================
#define BM 128
#define BN 128
#define BK 64

__global__ __launch_bounds__(256, 2) void gemm_x_wt_kernel(
    const float* __restrict__ X,
    const short* __restrict__ WT,
    float* __restrict__ C)
{
    __shared__ short As2[BM * BK];
    __shared__ short Bs2[BN * BK];

    const int bn = blockIdx.x;
    const int bm = blockIdx.y;
    const int tid  = threadIdx.x;
    const int lane = tid & 63;
    const int wid  = tid >> 6;
    const int wr   = wid >> 1;
    const int wc   = wid & 1;

    const int row0 = bm * BM;
    const int col0 = bn * BN;
    const int frow = lane & 15;
    const int fk   = (lane >> 4) * 8;

    f32x4 acc[4][4] = {};

    for (int kt = 0; kt < IN_F / BK; ++kt) {
        float4 a0[4], a1[4];
#pragma unroll
        for (int j = 0; j < 4; ++j) {
            const int flat = (j * 256 + tid) * 8;
            const int r = flat >> 6;
            const int c = flat & (BK - 1);
            const float* src = X + (size_t)(row0 + r) * IN_F + kt * BK + c;
            a0[j] = *reinterpret_cast<const float4*>(src);
            a1[j] = *reinterpret_cast<const float4*>(src + 4);
        }
        __syncthreads();
#pragma unroll
        for (int j = 0; j < 4; ++j) {
            const int flat = (j * 256 + tid) * 8;
            const int r = flat >> 6;
            const int c = flat & (BK - 1);
            load_lds16(WT + (size_t)(col0 + r) * IN_F + kt * BK + c, &Bs2[flat]);
        }
#pragma unroll
        for (int j = 0; j < 4; ++j) {
            const int flat = (j * 256 + tid) * 8;
            bf16x8 h;
            h[0] = f2bf(a0[j].x); h[1] = f2bf(a0[j].y);
            h[2] = f2bf(a0[j].z); h[3] = f2bf(a0[j].w);
            h[4] = f2bf(a1[j].x); h[5] = f2bf(a1[j].y);
            h[6] = f2bf(a1[j].z); h[7] = f2bf(a1[j].w);
            *reinterpret_cast<bf16x8*>(&As2[flat]) = h;
        }
        __syncthreads();
#pragma unroll
        for (int s = 0; s < 2; ++s) {
            bf16x8 af[4], bfr[4];
#pragma unroll
            for (int m = 0; m < 4; ++m) {
                const int row = wr * 64 + m * 16 + frow;
                af[m] = *reinterpret_cast<const bf16x8*>(&As2[row * BK + s * 32 + fk]);
            }
#pragma unroll
            for (int n = 0; n < 4; ++n) {
                const int col = wc * 64 + n * 16 + frow;
                bfr[n] = *reinterpret_cast<const bf16x8*>(&Bs2[col * BK + s * 32 + fk]);
            }
#pragma unroll
            for (int m = 0; m < 4; ++m)
#pragma unroll
                for (int n = 0; n < 4; ++n)
                    acc[m][n] = __builtin_amdgcn_mfma_f32_16x16x32_bf16(
                        af[m], bfr[n], acc[m][n], 0, 0, 0);
        }
    }

    const int crow = (lane >> 4) * 4;
    const int ccol = lane & 15;
#pragma unroll
    for (int m = 0; m < 4; ++m)
#pragma unroll
        for (int n = 0; n < 4; ++n)
#pragma unroll
            for (int r = 0; r < 4; ++r) {
                const int row = row0 + wr * 64 + m * 16 + crow + r;
                const int col = col0 + wc * 64 + n * 16 + ccol;
                C[(size_t)row * OUT_F + col] = acc[m][n][r];
            }
}

// ============================================================================
extern "C" void kernel_launch(void* const* d_in, const int* in_sizes, int n_in,
                              void* d_out, int out_size, void* d_ws, size_t ws_size,
                              hipStream_t stream) {
    const float* x       = (const float*)d_in[0];
    const int*   qweight = (const int*)  d_in[1];
    const int*   qzeros  = (const int*)  d_in[2];
    const float* scales  = (const float*)d_in[3];
    float*       out     = (float*)d_out;

    const size_t WT_BYTES = (size_t)OUT_F * IN_F * 2;   // 33.5 MB
    const size_t XB_BYTES = (size_t)M_ROWS * IN_F * 2;  // 67.1 MB

    short* wt = (short*)d_ws;

    dequant_wt_kernel<<<(OUT_F * (IN_F / 8)) / 256, 256, 0, stream>>>(
        qweight, qzeros, scales, wt);

    if (ws_size >= WT_BYTES + XB_BYTES) {
        short* xb = (short*)((char*)d_ws + WT_BYTES);
        xconv_kernel<<<(M_ROWS * IN_F / 8) / 256, 256, 0, stream>>>(x, xb);
        dim3 grid(OUT_F / 256, M_ROWS / 256);   // (16, 32)
        gemm8_kernel<<<grid, 512, 0, stream>>>(xb, wt, out);
    } else {
        dim3 grid(OUT_F / BN, M_ROWS / BM);     // (32, 64)
        gemm_x_wt_kernel<<<grid, 256, 0, stream>>>(x, wt, out);
    }
}